// Round 1
// baseline (2645.056 us; speedup 1.0000x reference)
//
#include <hip/hip_runtime.h>
#include <math.h>

// GeneralizedNeuralODE: out[b] = w_out . Phi_{tmin->tmax}( h0[b, rank63] ) + b_out
//   h0[b,r] = x[b,r,1:17] @ w_in + b_in
//   y' = tanh(y @ w1 + b1) @ w2 + b2   (autonomous)
//   rank63 = stable rank of x[b,63,0] within x[b,:,0]
// Fixed-step RK4, N=128 steps (global err ~1e-7, well under reference rtol=1e-5).

#define NB     128
#define NW     64
#define NF     17
#define NH     256
#define NSTEP  128
#define NWAVE  8   // 512 threads

__global__ __launch_bounds__(512, 2) void node_rk4_kernel(
    const float* __restrict__ x,
    const float* __restrict__ w_in, const float* __restrict__ b_in,
    const float* __restrict__ w1,   const float* __restrict__ b1,
    const float* __restrict__ w2,   const float* __restrict__ b2,
    const float* __restrict__ w_out,const float* __restrict__ b_out,
    float* __restrict__ out)
{
    __shared__ float s_v[NH];            // matvec input vector (current stage state)
    __shared__ float s_z[NH];            // tanh intermediate
    __shared__ float s_part[NWAVE][NH];  // per-wave partial sums
    __shared__ float s_red[NWAVE];

    const int b    = blockIdx.x;
    const int tid  = threadIdx.x;
    const int wave = tid >> 6;
    const int lane = tid & 63;

    const float* xb = x + b * (NW * NF);

    // ---- t-row analysis: min, max, stable rank of t[63] (redundant per wave) ----
    float tl  = xb[lane * NF];           // t value for window w = lane
    float t63 = __shfl(tl, 63);
    float tmn = tl, tmx = tl;
    #pragma unroll
    for (int off = 32; off > 0; off >>= 1) {
        tmn = fminf(tmn, __shfl_xor(tmn, off));
        tmx = fmaxf(tmx, __shfl_xor(tmx, off));
    }
    unsigned long long blt = __ballot((tl < t63) || (tl == t63 && lane < 63));
    const int   rank = __popcll(blt);
    const float h    = (tmx - tmn) / (float)NSTEP;

    // ---- h0 row: y0[j] = b_in[j] + sum_f x[b,rank,1+f] * w_in[f][j] ----
    float yA = 0.f;   // authoritative state component (tid < NH)
    if (tid < NH) {
        const float* xr = xb + rank * NF + 1;
        float acc = b_in[tid];
        #pragma unroll
        for (int f = 0; f < NF - 1; ++f)
            acc = fmaf(xr[f], w_in[f * NH + tid], acc);
        yA = acc;
        s_v[tid] = acc;
    }
    __syncthreads();

    // matvec: r[j] = bias[j] + sum_i sin_[i] * wm[i][j]; valid for tid < NH
    auto matvec = [&](const float* __restrict__ wm,
                      const float* __restrict__ bias,
                      const float* sin_) -> float {
        const float* wrow = wm + (wave * 32) * NH + (lane << 2);
        float ax = 0.f, ay = 0.f, az = 0.f, aw = 0.f;
        #pragma unroll
        for (int q = 0; q < 8; ++q) {
            float4 vi = *(const float4*)(sin_ + wave * 32 + (q << 2));
            float4 wa = *(const float4*)(wrow + (q * 4 + 0) * NH);
            float4 wb = *(const float4*)(wrow + (q * 4 + 1) * NH);
            float4 wc = *(const float4*)(wrow + (q * 4 + 2) * NH);
            float4 wd = *(const float4*)(wrow + (q * 4 + 3) * NH);
            ax = fmaf(vi.x, wa.x, ax); ay = fmaf(vi.x, wa.y, ay);
            az = fmaf(vi.x, wa.z, az); aw = fmaf(vi.x, wa.w, aw);
            ax = fmaf(vi.y, wb.x, ax); ay = fmaf(vi.y, wb.y, ay);
            az = fmaf(vi.y, wb.z, az); aw = fmaf(vi.y, wb.w, aw);
            ax = fmaf(vi.z, wc.x, ax); ay = fmaf(vi.z, wc.y, ay);
            az = fmaf(vi.z, wc.z, az); aw = fmaf(vi.z, wc.w, aw);
            ax = fmaf(vi.w, wd.x, ax); ay = fmaf(vi.w, wd.y, ay);
            az = fmaf(vi.w, wd.z, az); aw = fmaf(vi.w, wd.w, aw);
        }
        float4 o; o.x = ax; o.y = ay; o.z = az; o.w = aw;
        *(float4*)&s_part[wave][lane << 2] = o;
        __syncthreads();
        float r = 0.f;
        if (tid < NH) {
            r = bias[tid];
            #pragma unroll
            for (int p = 0; p < NWAVE; ++p) r += s_part[p][tid];
        }
        return r;
    };

    // vf(y) = tanh(y@w1+b1) @ w2 + b2 ; input vector must be in sin_, returns r[tid]
    auto vf = [&](const float* sin_) -> float {
        float u = matvec(w1, b1, sin_);
        if (tid < NH) s_z[tid] = tanhf(u);
        __syncthreads();
        return matvec(w2, b2, s_z);
    };

    // ---- RK4 time loop ----
    float kacc = 0.f;
    for (int step = 0; step < NSTEP; ++step) {
        float r1 = vf(s_v);
        if (tid < NH) { kacc = r1;                 s_v[tid] = fmaf(0.5f * h, r1, yA); }
        __syncthreads();
        float r2 = vf(s_v);
        if (tid < NH) { kacc = fmaf(2.f, r2, kacc); s_v[tid] = fmaf(0.5f * h, r2, yA); }
        __syncthreads();
        float r3 = vf(s_v);
        if (tid < NH) { kacc = fmaf(2.f, r3, kacc); s_v[tid] = fmaf(h, r3, yA); }
        __syncthreads();
        float r4 = vf(s_v);
        if (tid < NH) { yA = fmaf(h / 6.f, kacc + r4, yA); s_v[tid] = yA; }
        __syncthreads();
    }

    // ---- out[b] = b_out + sum_j y[j] * w_out[j] ----
    float p = (tid < NH) ? yA * w_out[tid] : 0.f;
    #pragma unroll
    for (int off = 32; off > 0; off >>= 1) p += __shfl_xor(p, off);
    if (lane == 0) s_red[wave] = p;
    __syncthreads();
    if (tid == 0) {
        float s = b_out[0];
        #pragma unroll
        for (int q = 0; q < NWAVE; ++q) s += s_red[q];
        out[b] = s;
    }
}

extern "C" void kernel_launch(void* const* d_in, const int* in_sizes, int n_in,
                              void* d_out, int out_size, void* d_ws, size_t ws_size,
                              hipStream_t stream) {
    const float* x     = (const float*)d_in[0];
    const float* w_in  = (const float*)d_in[1];
    const float* b_in  = (const float*)d_in[2];
    const float* w1    = (const float*)d_in[3];
    const float* b1    = (const float*)d_in[4];
    const float* w2    = (const float*)d_in[5];
    const float* b2    = (const float*)d_in[6];
    const float* w_out = (const float*)d_in[7];
    const float* b_out = (const float*)d_in[8];

    node_rk4_kernel<<<dim3(NB), dim3(512), 0, stream>>>(
        x, w_in, b_in, w1, b1, w2, b2, w_out, b_out, (float*)d_out);
}